// Round 1
// baseline (391.421 us; speedup 1.0000x reference)
//
#include <hip/hip_runtime.h>
#include <hip/hip_bf16.h>

typedef float f32x4 __attribute__((ext_vector_type(4)));
typedef __bf16 bf16x8 __attribute__((ext_vector_type(8)));

constexpr int B = 8, L = 1024, S = 1024, D = 256, V = 256, H = 8;
constexpr float SCALE = 0.17677669529663687f; // 1/sqrt(32)

__device__ __forceinline__ bf16x8 load_cvt8(const float* __restrict__ p) {
  const float4 a = *reinterpret_cast<const float4*>(p);
  const float4 b = *reinterpret_cast<const float4*>(p + 4);
  bf16x8 r;
  r[0] = (__bf16)a.x; r[1] = (__bf16)a.y; r[2] = (__bf16)a.z; r[3] = (__bf16)a.w;
  r[4] = (__bf16)b.x; r[5] = (__bf16)b.y; r[6] = (__bf16)b.z; r[7] = (__bf16)b.w;
  return r;
}

// ---------------------------------------------------------------------------
// Kernel 1: the five projection GEMMs (M=8192, N=256, K=256), y = x @ W^T.
// blockIdx.z selects projection. Output bf16.
//   z=0: qs = (q@Wqs^T)*SCALE   -> [B,L,H,32]
//   z=1: qo = (q@Wqo^T)*SCALE   -> [B,L,H,32]
//   z=2: ks =  k@Wks^T          -> [B,S,H,32]
//   z=3: ko =  k@Wko^T          -> [B,S,H,32]
//   z=4: vht = (v@Wv^T)^T       -> [B,H,32,S]  (transposed via LDS)
// ---------------------------------------------------------------------------
__global__ __launch_bounds__(256) void proj_kernel(
    const float* __restrict__ q, const float* __restrict__ k, const float* __restrict__ v,
    const float* __restrict__ wqs, const float* __restrict__ wqo,
    const float* __restrict__ wks, const float* __restrict__ wko,
    const float* __restrict__ wv,
    __bf16* __restrict__ qs, __bf16* __restrict__ qo,
    __bf16* __restrict__ ksl, __bf16* __restrict__ kol,
    __bf16* __restrict__ vht)
{
  const int proj = blockIdx.z;
  const float* X; const float* W;
  if (proj == 0)      { X = q; W = wqs; }
  else if (proj == 1) { X = q; W = wqo; }
  else if (proj == 2) { X = k; W = wks; }
  else if (proj == 3) { X = k; W = wko; }
  else                { X = v; W = wv;  }

  const int tid = threadIdx.x;
  const int w = tid >> 6, lane = tid & 63;
  const int cl = lane & 15, g = lane >> 4;
  const int m0 = blockIdx.y * 64 + w * 16;
  const int n0 = blockIdx.x * 64;

  f32x4 zf = {0.f, 0.f, 0.f, 0.f};
  f32x4 acc[4] = {zf, zf, zf, zf};
  const float* arow = X + (size_t)(m0 + cl) * 256 + g * 8;
  #pragma unroll
  for (int kk = 0; kk < 8; ++kk) {
    bf16x8 af = load_cvt8(arow + kk * 32);
    #pragma unroll
    for (int nt = 0; nt < 4; ++nt) {
      bf16x8 bfr = load_cvt8(W + (size_t)(n0 + nt * 16 + cl) * 256 + kk * 32 + g * 8);
      acc[nt] = __builtin_amdgcn_mfma_f32_16x16x32_bf16(af, bfr, acc[nt], 0, 0, 0);
    }
  }
  if (proj < 2) {
    #pragma unroll
    for (int nt = 0; nt < 4; ++nt)
      #pragma unroll
      for (int r = 0; r < 4; ++r) acc[nt][r] *= SCALE;
  }

  __shared__ float ct[64][65];
  if (proj < 4) {
    __bf16* Y = (proj == 0) ? qs : (proj == 1) ? qo : (proj == 2) ? ksl : kol;
    #pragma unroll
    for (int nt = 0; nt < 4; ++nt) {
      int n = n0 + nt * 16 + cl;
      #pragma unroll
      for (int r = 0; r < 4; ++r)
        Y[(size_t)(m0 + g * 4 + r) * 256 + n] = (__bf16)acc[nt][r];
    }
  } else {
    // stage f32 tile, transpose, write [B,H,32,S] bf16
    #pragma unroll
    for (int nt = 0; nt < 4; ++nt) {
      #pragma unroll
      for (int r = 0; r < 4; ++r)
        ct[w * 16 + g * 4 + r][nt * 16 + cl] = acc[nt][r];
    }
    __syncthreads();
    int n_local = tid >> 2;          // 0..63  output row (h*32+vd within this n-block)
    int sc = (tid & 3) << 4;         // 0,16,32,48  s-chunk
    int n = n0 + n_local;
    int hh = n >> 5, vd = n & 31;
    int bb = (blockIdx.y * 64) >> 10;
    int sbase = (blockIdx.y * 64) & 1023;
    __bf16* dst = vht + (((size_t)(bb * H + hh)) * 32 + vd) * 1024 + sbase + sc;
    bf16x8 o0, o1;
    #pragma unroll
    for (int j = 0; j < 8; ++j) o0[j] = (__bf16)ct[sc + j][n_local];
    #pragma unroll
    for (int j = 0; j < 8; ++j) o1[j] = (__bf16)ct[sc + 8 + j][n_local];
    *reinterpret_cast<bf16x8*>(dst) = o0;
    *reinterpret_cast<bf16x8*>(dst + 8) = o1;
  }
}

// ---------------------------------------------------------------------------
// Kernel 2: agent-aware attention.
// Block = (b, 16 query rows). 4 waves, wave w owns s in [w*256, w*256+256).
// Loops heads; logits in registers (16 x f32x4 D-frags); select(self/other)
// by identity; +mask (LDS bf16); softmax across waves via LDS reduce;
// P -> LDS (per-wave) -> MFMA A-frag for PV; PV partials reduced via LDS.
// att_mean accumulated in registers across heads, written once.
// ---------------------------------------------------------------------------
__global__ __launch_bounds__(256) void attn_kernel(
    const __bf16* __restrict__ qs, const __bf16* __restrict__ qo,
    const __bf16* __restrict__ ksl, const __bf16* __restrict__ kol,
    const __bf16* __restrict__ vht,
    const int* __restrict__ qid, const int* __restrict__ kid,
    const float* __restrict__ mask,
    float* __restrict__ out_pre, float* __restrict__ att_mean)
{
  const int b = blockIdx.y;
  const int l0 = blockIdx.x * 16;
  const int tid = threadIdx.x;
  const int w = tid >> 6, lane = tid & 63;
  const int cl = lane & 15, g = lane >> 4;
  const int sw = w * 256;

  __shared__ __bf16 pbuf[4][16][264];     // per-wave P tile (row pad -> ~2-way banks)
  __shared__ __bf16 mask_lds[16][1032];
  __shared__ float  obuf[4][16][32];
  __shared__ int    kid_lds[1024];
  __shared__ int    qid_lds[16];
  __shared__ float  redmax[4][16];
  __shared__ float  redsum[4][16];

  {
    const float* mrow = mask + ((size_t)b * L + l0) * S;
    for (int idx = tid; idx < 16 * 256; idx += 256) {
      int row = idx >> 8;
      int c4 = (idx & 255) << 2;
      float4 mv = *reinterpret_cast<const float4*>(mrow + (size_t)row * S + c4);
      mask_lds[row][c4 + 0] = (__bf16)mv.x;
      mask_lds[row][c4 + 1] = (__bf16)mv.y;
      mask_lds[row][c4 + 2] = (__bf16)mv.z;
      mask_lds[row][c4 + 3] = (__bf16)mv.w;
    }
    for (int i = tid; i < S; i += 256) kid_lds[i] = kid[b * S + i];
    if (tid < 16) qid_lds[tid] = qid[b * L + l0 + tid];
  }
  __syncthreads();

  int qid_r[4];
  #pragma unroll
  for (int r = 0; r < 4; ++r) qid_r[r] = qid_lds[g * 4 + r];
  int kid_st[16];
  #pragma unroll
  for (int st = 0; st < 16; ++st) kid_st[st] = kid_lds[sw + st * 16 + cl];

  f32x4 zf = {0.f, 0.f, 0.f, 0.f};
  f32x4 att_acc[16];
  #pragma unroll
  for (int st = 0; st < 16; ++st) att_acc[st] = zf;

  for (int h = 0; h < H; ++h) {
    const size_t qoff = (((size_t)(b * L + l0 + cl)) * H + h) * 32 + g * 8;
    bf16x8 qsf = *reinterpret_cast<const bf16x8*>(qs + qoff);
    bf16x8 qof = *reinterpret_cast<const bf16x8*>(qo + qoff);

    f32x4 logit[16];
    #pragma unroll
    for (int st = 0; st < 16; ++st) {
      const size_t koff = (((size_t)(b * S + sw + st * 16 + cl)) * H + h) * 32 + g * 8;
      bf16x8 kf1 = *reinterpret_cast<const bf16x8*>(ksl + koff);
      bf16x8 kf2 = *reinterpret_cast<const bf16x8*>(kol + koff);
      f32x4 aself = __builtin_amdgcn_mfma_f32_16x16x32_bf16(qsf, kf1, zf, 0, 0, 0);
      f32x4 aoth  = __builtin_amdgcn_mfma_f32_16x16x32_bf16(qof, kf2, zf, 0, 0, 0);
      int kc = kid_st[st];
      #pragma unroll
      for (int r = 0; r < 4; ++r) {
        float mv = (float)mask_lds[g * 4 + r][sw + st * 16 + cl];
        logit[st][r] = ((qid_r[r] == kc) ? aself[r] : aoth[r]) + mv;
      }
    }

    // ---- softmax over full S (cross-wave) ----
    float rmax[4];
    #pragma unroll
    for (int r = 0; r < 4; ++r) {
      float m = logit[0][r];
      #pragma unroll
      for (int st = 1; st < 16; ++st) m = fmaxf(m, logit[st][r]);
      #pragma unroll
      for (int d = 1; d < 16; d <<= 1) m = fmaxf(m, __shfl_xor(m, d));
      rmax[r] = m;
    }
    if (cl == 0) {
      #pragma unroll
      for (int r = 0; r < 4; ++r) redmax[w][g * 4 + r] = rmax[r];
    }
    __syncthreads();
    float gmax[4], rsum[4];
    #pragma unroll
    for (int r = 0; r < 4; ++r) {
      int row = g * 4 + r;
      gmax[r] = fmaxf(fmaxf(redmax[0][row], redmax[1][row]),
                      fmaxf(redmax[2][row], redmax[3][row]));
      rsum[r] = 0.f;
    }
    #pragma unroll
    for (int st = 0; st < 16; ++st) {
      #pragma unroll
      for (int r = 0; r < 4; ++r) {
        float p = __expf(logit[st][r] - gmax[r]);
        logit[st][r] = p;
        rsum[r] += p;
      }
    }
    #pragma unroll
    for (int r = 0; r < 4; ++r) {
      float sv = rsum[r];
      #pragma unroll
      for (int d = 1; d < 16; d <<= 1) sv += __shfl_xor(sv, d);
      rsum[r] = sv;
    }
    if (cl == 0) {
      #pragma unroll
      for (int r = 0; r < 4; ++r) redsum[w][g * 4 + r] = rsum[r];
    }
    __syncthreads();
    float inv[4];
    #pragma unroll
    for (int r = 0; r < 4; ++r) {
      int row = g * 4 + r;
      inv[r] = 1.f / (redsum[0][row] + redsum[1][row] + redsum[2][row] + redsum[3][row]);
    }
    #pragma unroll
    for (int st = 0; st < 16; ++st) {
      #pragma unroll
      for (int r = 0; r < 4; ++r) {
        float pf = logit[st][r] * inv[r];
        att_acc[st][r] += pf;
        pbuf[w][g * 4 + r][st * 16 + cl] = (__bf16)pf;
      }
    }
    __syncthreads();

    // ---- PV over this wave's s-range ----
    f32x4 oa0 = zf, oa1 = zf;
    const __bf16* vbase = vht + (((size_t)(b * H + h)) * 32) * 1024;
    #pragma unroll
    for (int kt = 0; kt < 8; ++kt) {
      bf16x8 pa  = *reinterpret_cast<const bf16x8*>(&pbuf[w][cl][kt * 32 + g * 8]);
      bf16x8 vb0 = *reinterpret_cast<const bf16x8*>(vbase + (size_t)cl * 1024 + sw + kt * 32 + g * 8);
      bf16x8 vb1 = *reinterpret_cast<const bf16x8*>(vbase + (size_t)(16 + cl) * 1024 + sw + kt * 32 + g * 8);
      oa0 = __builtin_amdgcn_mfma_f32_16x16x32_bf16(pa, vb0, oa0, 0, 0, 0);
      oa1 = __builtin_amdgcn_mfma_f32_16x16x32_bf16(pa, vb1, oa1, 0, 0, 0);
    }
    #pragma unroll
    for (int r = 0; r < 4; ++r) {
      obuf[w][g * 4 + r][cl]      = oa0[r];
      obuf[w][g * 4 + r][16 + cl] = oa1[r];
    }
    __syncthreads();
    for (int i = tid; i < 512; i += 256) {
      int row = i >> 5, vd = i & 31;
      float sv = obuf[0][row][vd] + obuf[1][row][vd] + obuf[2][row][vd] + obuf[3][row][vd];
      out_pre[((size_t)(b * L + l0 + row)) * V + h * 32 + vd] = sv;
    }
    __syncthreads();
  }

  // ---- write attention.sum(heads)/H ----
  float* am = att_mean + ((size_t)b * L + l0) * S;
  #pragma unroll
  for (int st = 0; st < 16; ++st) {
    #pragma unroll
    for (int r = 0; r < 4; ++r)
      am[(size_t)(g * 4 + r) * S + sw + st * 16 + cl] = att_acc[st][r] * 0.125f;
  }
}

// ---------------------------------------------------------------------------
// Kernel 3: fc  out = out_pre @ fc_w^T + fc_b   (f32 out)
// ---------------------------------------------------------------------------
__global__ __launch_bounds__(256) void fc_kernel(
    const float* __restrict__ xp, const float* __restrict__ fcw,
    const float* __restrict__ fcb, float* __restrict__ out)
{
  const int tid = threadIdx.x;
  const int w = tid >> 6, lane = tid & 63;
  const int cl = lane & 15, g = lane >> 4;
  const int m0 = blockIdx.y * 64 + w * 16;
  const int n0 = blockIdx.x * 64;
  f32x4 zf = {0.f, 0.f, 0.f, 0.f};
  f32x4 acc[4] = {zf, zf, zf, zf};
  const float* arow = xp + (size_t)(m0 + cl) * 256 + g * 8;
  #pragma unroll
  for (int kk = 0; kk < 8; ++kk) {
    bf16x8 af = load_cvt8(arow + kk * 32);
    #pragma unroll
    for (int nt = 0; nt < 4; ++nt) {
      bf16x8 bfr = load_cvt8(fcw + (size_t)(n0 + nt * 16 + cl) * 256 + kk * 32 + g * 8);
      acc[nt] = __builtin_amdgcn_mfma_f32_16x16x32_bf16(af, bfr, acc[nt], 0, 0, 0);
    }
  }
  #pragma unroll
  for (int nt = 0; nt < 4; ++nt) {
    int n = n0 + nt * 16 + cl;
    float bias = fcb[n];
    #pragma unroll
    for (int r = 0; r < 4; ++r)
      out[(size_t)(m0 + g * 4 + r) * 256 + n] = acc[nt][r] + bias;
  }
}

// ---------------------------------------------------------------------------
extern "C" void kernel_launch(void* const* d_in, const int* in_sizes, int n_in,
                              void* d_out, int out_size, void* d_ws, size_t ws_size,
                              hipStream_t stream) {
  const float* q    = (const float*)d_in[0];
  const float* k    = (const float*)d_in[1];
  const float* v    = (const float*)d_in[2];
  const int*   qid  = (const int*)d_in[3];
  const int*   kid  = (const int*)d_in[4];
  const float* mask = (const float*)d_in[5];
  const float* wqs  = (const float*)d_in[6];
  const float* wqo  = (const float*)d_in[7];
  const float* wks  = (const float*)d_in[8];
  const float* wko  = (const float*)d_in[9];
  const float* wv   = (const float*)d_in[10];
  const float* fcw  = (const float*)d_in[11];
  const float* fcb  = (const float*)d_in[12];

  char* ws = (char*)d_ws;
  const size_t ACT = (size_t)B * L * D * sizeof(__bf16); // 4 MB per activation
  __bf16* qs  = (__bf16*)(ws + 0 * ACT);
  __bf16* qo  = (__bf16*)(ws + 1 * ACT);
  __bf16* ksl = (__bf16*)(ws + 2 * ACT);
  __bf16* kol = (__bf16*)(ws + 3 * ACT);
  __bf16* vht = (__bf16*)(ws + 4 * ACT);
  float* out_pre = (float*)(ws + 5 * ACT);   // 8 MB f32

  float* out0 = (float*)d_out;
  float* att_mean = out0 + (size_t)B * L * V;

  proj_kernel<<<dim3(4, 128, 5), 256, 0, stream>>>(q, k, v, wqs, wqo, wks, wko, wv,
                                                   qs, qo, ksl, kol, vht);
  attn_kernel<<<dim3(64, 8), 256, 0, stream>>>(qs, qo, ksl, kol, vht, qid, kid, mask,
                                               out_pre, att_mean);
  fc_kernel<<<dim3(4, 128), 256, 0, stream>>>(out_pre, fcw, fcb, out0);
}

// Round 4
// 260.981 us; speedup vs baseline: 1.4998x; 1.4998x over previous
//
#include <hip/hip_runtime.h>
#include <hip/hip_bf16.h>

typedef float f32x4 __attribute__((ext_vector_type(4)));
typedef __bf16 bf16x8 __attribute__((ext_vector_type(8)));
typedef unsigned short us4 __attribute__((ext_vector_type(4)));

constexpr int B = 8, L = 1024, S = 1024, H = 8;
constexpr float SCALE = 0.17677669529663687f; // 1/sqrt(32)

__device__ __forceinline__ unsigned short bfbits(float x) {
  return __builtin_bit_cast(unsigned short, (__bf16)x);
}
__device__ __forceinline__ unsigned int pk2(float a, float b) {
  return ((unsigned int)bfbits(b) << 16) | (unsigned int)bfbits(a);
}
__device__ __forceinline__ float unpk_lo(unsigned int u) {
  return __builtin_bit_cast(float, u << 16);
}
__device__ __forceinline__ float unpk_hi(unsigned int u) {
  return __builtin_bit_cast(float, u & 0xffff0000u);
}

// ---------------------------------------------------------------------------
// Kernel 1: five projection GEMMs (M=8192,N=256,K=256), y = x@W^T, bf16 out.
// A,W staged via LDS (coalesced f32 loads, one-time bf16 convert).
// Outputs in fragment-major layouts:
//   z=0..3: [B,H,T,32]   (q_self*SCALE, q_other*SCALE, k_self, k_other)
//   z=4   : [B,H,S/32,32vd,32s] tiles (v, transposed via LDS)
// ---------------------------------------------------------------------------
__global__ __launch_bounds__(256) void proj_kernel(
    const float* __restrict__ q, const float* __restrict__ k, const float* __restrict__ v,
    const float* __restrict__ wqs, const float* __restrict__ wqo,
    const float* __restrict__ wks, const float* __restrict__ wko,
    const float* __restrict__ wv,
    __bf16* __restrict__ qs, __bf16* __restrict__ qo,
    __bf16* __restrict__ ksl, __bf16* __restrict__ kol,
    __bf16* __restrict__ vht)
{
  const int proj = blockIdx.z;
  const float* X; const float* W;
  if (proj == 0)      { X = q; W = wqs; }
  else if (proj == 1) { X = q; W = wqo; }
  else if (proj == 2) { X = k; W = wks; }
  else if (proj == 3) { X = k; W = wko; }
  else                { X = v; W = wv;  }

  __shared__ __align__(16) char smem[2 * 64 * 264 * 2];
  __bf16 (*At)[264] = (__bf16(*)[264])smem;
  __bf16 (*Wt)[264] = (__bf16(*)[264])(smem + 64 * 264 * 2);
  float  (*ct)[65]  = (float(*)[65])smem;   // aliases At; used only post-sync (proj==4)

  const int tid = threadIdx.x;
  const int m0 = blockIdx.y * 64, n0 = blockIdx.x * 64;

  for (int i = tid; i < 4096; i += 256) {
    int row = i >> 6, c4 = (i & 63) << 2;
    float4 a  = *reinterpret_cast<const float4*>(X + (size_t)(m0 + row) * 256 + c4);
    float4 ww = *reinterpret_cast<const float4*>(W + (size_t)(n0 + row) * 256 + c4);
    us4 ap, wp;
    ap[0] = bfbits(a.x);  ap[1] = bfbits(a.y);  ap[2] = bfbits(a.z);  ap[3] = bfbits(a.w);
    wp[0] = bfbits(ww.x); wp[1] = bfbits(ww.y); wp[2] = bfbits(ww.z); wp[3] = bfbits(ww.w);
    *reinterpret_cast<us4*>(&At[row][c4]) = ap;
    *reinterpret_cast<us4*>(&Wt[row][c4]) = wp;
  }
  __syncthreads();

  const int w = tid >> 6, lane = tid & 63;
  const int cl = lane & 15, g = lane >> 4;

  f32x4 zf = {0.f, 0.f, 0.f, 0.f};
  f32x4 acc[4] = {zf, zf, zf, zf};
  #pragma unroll
  for (int kk = 0; kk < 8; ++kk) {
    bf16x8 af = *reinterpret_cast<const bf16x8*>(&At[w * 16 + cl][kk * 32 + g * 8]);
    #pragma unroll
    for (int nt = 0; nt < 4; ++nt) {
      bf16x8 bfr = *reinterpret_cast<const bf16x8*>(&Wt[nt * 16 + cl][kk * 32 + g * 8]);
      acc[nt] = __builtin_amdgcn_mfma_f32_16x16x32_bf16(af, bfr, acc[nt], 0, 0, 0);
    }
  }
  if (proj < 2) {
    #pragma unroll
    for (int nt = 0; nt < 4; ++nt)
      #pragma unroll
      for (int r = 0; r < 4; ++r) acc[nt][r] *= SCALE;
  }

  if (proj < 4) {
    __bf16* Y = (proj == 0) ? qs : (proj == 1) ? qo : (proj == 2) ? ksl : kol;
    #pragma unroll
    for (int nt = 0; nt < 4; ++nt) {
      int n = n0 + nt * 16 + cl;
      int h = n >> 5, hd = n & 31;
      #pragma unroll
      for (int r = 0; r < 4; ++r) {
        int m = m0 + w * 16 + g * 4 + r;
        int bb = m >> 10, t = m & 1023;
        Y[(((size_t)(bb * H + h)) * 1024 + t) * 32 + hd] = (__bf16)acc[nt][r];
      }
    }
  } else {
    __syncthreads();   // At/Wt dead; reuse as ct
    #pragma unroll
    for (int nt = 0; nt < 4; ++nt)
      #pragma unroll
      for (int r = 0; r < 4; ++r)
        ct[w * 16 + g * 4 + r][nt * 16 + cl] = acc[nt][r];
    __syncthreads();
    int n_local = tid >> 2;          // 0..63 (h*32+vd within n-block)
    int sc = (tid & 3) << 4;         // 0,16,32,48 s-chunk
    int n = n0 + n_local;
    int h = n >> 5, vd = n & 31;
    int bb = m0 >> 10;
    int sbase = m0 & 1023;
    int t32 = (sbase + sc) >> 5, off = (sbase + sc) & 31;
    __bf16* dst = vht + ((((size_t)(bb * H + h)) * 32 + t32)) * 1024 + vd * 32 + off;
    bf16x8 o0, o1;
    #pragma unroll
    for (int j = 0; j < 8; ++j) o0[j] = (__bf16)ct[sc + j][n_local];
    #pragma unroll
    for (int j = 0; j < 8; ++j) o1[j] = (__bf16)ct[sc + 8 + j][n_local];
    *reinterpret_cast<bf16x8*>(dst) = o0;
    *reinterpret_cast<bf16x8*>(dst + 8) = o1;
  }
}

// ---------------------------------------------------------------------------
// Kernel 2: agent-aware attention. Block = (b, 16 q-rows, head-group of 4).
// 4 waves, wave w owns s in [w*256, w*256+256). One barrier per head.
// Unnormalized exp(logit) written bf16 to pbuf in the QK loop; normalization
// applied during the PV readback (which also accumulates att_mean).
// ---------------------------------------------------------------------------
__global__ __launch_bounds__(256) void attn_kernel(
    const __bf16* __restrict__ qs, const __bf16* __restrict__ qo,
    const __bf16* __restrict__ ksl, const __bf16* __restrict__ kol,
    const __bf16* __restrict__ vht,
    const int* __restrict__ qid, const int* __restrict__ kid,
    const float* __restrict__ mask,
    float* __restrict__ out_part, __bf16* __restrict__ att_part)
{
  const int b = blockIdx.y;
  const int l0 = blockIdx.x * 16;
  const int hg = blockIdx.z;
  const int tid = threadIdx.x;
  const int w = tid >> 6, lane = tid & 63;
  const int cl = lane & 15, g = lane >> 4;
  const int sw = w * 256;

  __shared__ __align__(16) __bf16 pbuf[4][16][264];
  __shared__ float redsum[2][4][16];

  int qid_r[4];
  #pragma unroll
  for (int r = 0; r < 4; ++r) qid_r[r] = qid[b * L + l0 + g * 4 + r];
  int kid_st[16];
  #pragma unroll
  for (int st = 0; st < 16; ++st) kid_st[st] = kid[b * S + sw + st * 16 + cl];

  unsigned int mreg[16][2];
  {
    const float* mrow = mask + ((size_t)b * L + l0 + g * 4) * S + sw + cl;
    #pragma unroll
    for (int st = 0; st < 16; ++st) {
      float a0 = mrow[(size_t)0 * S + st * 16];
      float a1 = mrow[(size_t)1 * S + st * 16];
      float a2 = mrow[(size_t)2 * S + st * 16];
      float a3 = mrow[(size_t)3 * S + st * 16];
      mreg[st][0] = pk2(a0, a1);
      mreg[st][1] = pk2(a2, a3);
    }
  }

  f32x4 zf = {0.f, 0.f, 0.f, 0.f};
  float att_acc[8][8];
  #pragma unroll
  for (int kt = 0; kt < 8; ++kt)
    #pragma unroll
    for (int j = 0; j < 8; ++j) att_acc[kt][j] = 0.f;

  const size_t PSZ = (size_t)B * L * 256;

  for (int hi = 0; hi < 4; ++hi) {
    const int h = hg * 4 + hi;
    const int par = hi & 1;
    const size_t hb = ((size_t)(b * H + h)) * 1024;

    bf16x8 qsf = *reinterpret_cast<const bf16x8*>(qs + (hb + l0 + cl) * 32 + g * 8);
    bf16x8 qof = *reinterpret_cast<const bf16x8*>(qo + (hb + l0 + cl) * 32 + g * 8);
    const __bf16* kb1 = ksl + (hb + sw) * 32;
    const __bf16* kb2 = kol + (hb + sw) * 32;

    float rsum[4] = {0.f, 0.f, 0.f, 0.f};
    #pragma unroll
    for (int st = 0; st < 16; ++st) {
      bf16x8 kf1 = *reinterpret_cast<const bf16x8*>(kb1 + st * 512 + cl * 32 + g * 8);
      bf16x8 kf2 = *reinterpret_cast<const bf16x8*>(kb2 + st * 512 + cl * 32 + g * 8);
      f32x4 as = __builtin_amdgcn_mfma_f32_16x16x32_bf16(qsf, kf1, zf, 0, 0, 0);
      f32x4 ao = __builtin_amdgcn_mfma_f32_16x16x32_bf16(qof, kf2, zf, 0, 0, 0);
      int kc = kid_st[st];
      float mv[4] = {unpk_lo(mreg[st][0]), unpk_hi(mreg[st][0]),
                     unpk_lo(mreg[st][1]), unpk_hi(mreg[st][1])};
      #pragma unroll
      for (int r = 0; r < 4; ++r) {
        float lg = ((qid_r[r] == kc) ? as[r] : ao[r]) + mv[r];
        float p = __expf(fminf(lg, 60.f));
        pbuf[w][g * 4 + r][st * 16 + cl] = (__bf16)p;
        rsum[r] += p;
      }
    }

    // row-sum across cl lanes, then across waves
    #pragma unroll
    for (int r = 0; r < 4; ++r) {
      float sv = rsum[r];
      sv += __shfl_xor(sv, 1); sv += __shfl_xor(sv, 2);
      sv += __shfl_xor(sv, 4); sv += __shfl_xor(sv, 8);
      rsum[r] = sv;
    }
    if (cl == 0) {
      #pragma unroll
      for (int r = 0; r < 4; ++r) redsum[par][w][g * 4 + r] = rsum[r];
    }
    __syncthreads();
    float zrow = redsum[par][0][cl] + redsum[par][1][cl] +
                 redsum[par][2][cl] + redsum[par][3][cl];
    float inv_cl = 1.0f / zrow;
    float invq[4];
    #pragma unroll
    for (int r = 0; r < 4; ++r) invq[r] = __shfl(inv_cl, g * 4 + r);

    // PV + att accumulation (reads own wave's pbuf only; no barrier needed)
    f32x4 oa0 = zf, oa1 = zf;
    const __bf16* vb = vht + ((size_t)(b * H + h)) * 32 * 1024 + (size_t)w * 8 * 1024;
    #pragma unroll
    for (int kt = 0; kt < 8; ++kt) {
      bf16x8 pa = *reinterpret_cast<const bf16x8*>(&pbuf[w][cl][kt * 32 + g * 8]);
      #pragma unroll
      for (int j = 0; j < 8; ++j) att_acc[kt][j] += (float)pa[j] * inv_cl;
      bf16x8 v0 = *reinterpret_cast<const bf16x8*>(vb + kt * 1024 + cl * 32 + g * 8);
      bf16x8 v1 = *reinterpret_cast<const bf16x8*>(vb + kt * 1024 + 512 + cl * 32 + g * 8);
      oa0 = __builtin_amdgcn_mfma_f32_16x16x32_bf16(pa, v0, oa0, 0, 0, 0);
      oa1 = __builtin_amdgcn_mfma_f32_16x16x32_bf16(pa, v1, oa1, 0, 0, 0);
    }
    float* op = out_part + (size_t)w * PSZ + ((size_t)(b * 1024 + l0)) * 256 + h * 32;
    #pragma unroll
    for (int r = 0; r < 4; ++r) {
      op[(size_t)(g * 4 + r) * 256 + cl]      = oa0[r] * invq[r];
      op[(size_t)(g * 4 + r) * 256 + cl + 16] = oa1[r] * invq[r];
    }
  }

  // att partial (sum of this head-group's 4 heads, /8) -> bf16
  __bf16* ap = att_part + (size_t)hg * ((size_t)B * L * S) +
               ((size_t)(b * 1024 + l0 + cl)) * 1024 + sw + g * 8;
  #pragma unroll
  for (int kt = 0; kt < 8; ++kt) {
    bf16x8 o;
    #pragma unroll
    for (int j = 0; j < 8; ++j) o[j] = (__bf16)(att_acc[kt][j] * 0.125f);
    *reinterpret_cast<bf16x8*>(ap + kt * 32) = o;
  }
}

// ---------------------------------------------------------------------------
// Kernel 3: fc  out = (sum of 4 out_part) @ fc_w^T + fc_b  (f32 out)
// ---------------------------------------------------------------------------
__global__ __launch_bounds__(256) void fc_kernel(
    const float* __restrict__ part, const float* __restrict__ fcw,
    const float* __restrict__ fcb, float* __restrict__ out)
{
  __shared__ __align__(16) __bf16 At[64][264];
  __shared__ __align__(16) __bf16 Wt[64][264];
  const int tid = threadIdx.x;
  const int m0 = blockIdx.y * 64, n0 = blockIdx.x * 64;
  const size_t PSZ = (size_t)B * L * 256;

  for (int i = tid; i < 4096; i += 256) {
    int row = i >> 6, c4 = (i & 63) << 2;
    size_t off = (size_t)(m0 + row) * 256 + c4;
    float4 s0 = *reinterpret_cast<const float4*>(part + off);
    float4 s1 = *reinterpret_cast<const float4*>(part + PSZ + off);
    float4 s2 = *reinterpret_cast<const float4*>(part + 2 * PSZ + off);
    float4 s3 = *reinterpret_cast<const float4*>(part + 3 * PSZ + off);
    float4 ww = *reinterpret_cast<const float4*>(fcw + (size_t)(n0 + row) * 256 + c4);
    us4 ap, wp;
    ap[0] = bfbits(s0.x + s1.x + s2.x + s3.x);
    ap[1] = bfbits(s0.y + s1.y + s2.y + s3.y);
    ap[2] = bfbits(s0.z + s1.z + s2.z + s3.z);
    ap[3] = bfbits(s0.w + s1.w + s2.w + s3.w);
    wp[0] = bfbits(ww.x); wp[1] = bfbits(ww.y); wp[2] = bfbits(ww.z); wp[3] = bfbits(ww.w);
    *reinterpret_cast<us4*>(&At[row][c4]) = ap;
    *reinterpret_cast<us4*>(&Wt[row][c4]) = wp;
  }
  __syncthreads();

  const int w = tid >> 6, lane = tid & 63;
  const int cl = lane & 15, g = lane >> 4;
  f32x4 zf = {0.f, 0.f, 0.f, 0.f};
  f32x4 acc[4] = {zf, zf, zf, zf};
  #pragma unroll
  for (int kk = 0; kk < 8; ++kk) {
    bf16x8 af = *reinterpret_cast<const bf16x8*>(&At[w * 16 + cl][kk * 32 + g * 8]);
    #pragma unroll
    for (int nt = 0; nt < 4; ++nt) {
      bf16x8 bfr = *reinterpret_cast<const bf16x8*>(&Wt[nt * 16 + cl][kk * 32 + g * 8]);
      acc[nt] = __builtin_amdgcn_mfma_f32_16x16x32_bf16(af, bfr, acc[nt], 0, 0, 0);
    }
  }
  #pragma unroll
  for (int nt = 0; nt < 4; ++nt) {
    int n = n0 + nt * 16 + cl;
    float bias = fcb[n];
    #pragma unroll
    for (int r = 0; r < 4; ++r)
      out[(size_t)(m0 + w * 16 + g * 4 + r) * 256 + n] = acc[nt][r] + bias;
  }
}

// ---------------------------------------------------------------------------
// Kernel 4: att_mean = part0 + part1 (bf16 partials -> f32)
// ---------------------------------------------------------------------------
__global__ __launch_bounds__(256) void reduce_att_kernel(
    const __bf16* __restrict__ ap, float* __restrict__ am)
{
  const size_t APSZ = (size_t)B * L * S;
  size_t i = ((size_t)blockIdx.x * 256 + threadIdx.x) * 8;
  bf16x8 a = *reinterpret_cast<const bf16x8*>(ap + i);
  bf16x8 c = *reinterpret_cast<const bf16x8*>(ap + APSZ + i);
  float4 o0, o1;
  o0.x = (float)a[0] + (float)c[0]; o0.y = (float)a[1] + (float)c[1];
  o0.z = (float)a[2] + (float)c[2]; o0.w = (float)a[3] + (float)c[3];
  o1.x = (float)a[4] + (float)c[4]; o1.y = (float)a[5] + (float)c[5];
  o1.z = (float)a[6] + (float)c[6]; o1.w = (float)a[7] + (float)c[7];
  *reinterpret_cast<float4*>(am + i) = o0;
  *reinterpret_cast<float4*>(am + i + 4) = o1;
}

// ---------------------------------------------------------------------------
extern "C" void kernel_launch(void* const* d_in, const int* in_sizes, int n_in,
                              void* d_out, int out_size, void* d_ws, size_t ws_size,
                              hipStream_t stream) {
  const float* q    = (const float*)d_in[0];
  const float* k    = (const float*)d_in[1];
  const float* v    = (const float*)d_in[2];
  const int*   qid  = (const int*)d_in[3];
  const int*   kid  = (const int*)d_in[4];
  const float* mask = (const float*)d_in[5];
  const float* wqs  = (const float*)d_in[6];
  const float* wqo  = (const float*)d_in[7];
  const float* wks  = (const float*)d_in[8];
  const float* wko  = (const float*)d_in[9];
  const float* wv   = (const float*)d_in[10];
  const float* fcw  = (const float*)d_in[11];
  const float* fcb  = (const float*)d_in[12];

  char* ws = (char*)d_ws;
  const size_t ACT = (size_t)B * L * 256 * sizeof(__bf16);   // 4 MB
  __bf16* qs  = (__bf16*)(ws + 0 * ACT);
  __bf16* qo  = (__bf16*)(ws + 1 * ACT);
  __bf16* ksl = (__bf16*)(ws + 2 * ACT);
  __bf16* kol = (__bf16*)(ws + 3 * ACT);
  __bf16* vht = (__bf16*)(ws + 4 * ACT);
  float*  out_part = (float*)(ws + 5 * ACT);                  // 4 x 8 MB f32
  __bf16* att_part = (__bf16*)(ws + 5 * ACT + 4 * (size_t)B * L * 256 * 4); // 2 x 16 MB bf16

  float* out0 = (float*)d_out;
  float* att_mean = out0 + (size_t)B * L * 256;

  proj_kernel<<<dim3(4, 128, 5), 256, 0, stream>>>(q, k, v, wqs, wqo, wks, wko, wv,
                                                   qs, qo, ksl, kol, vht);
  attn_kernel<<<dim3(64, 8, 2), 256, 0, stream>>>(qs, qo, ksl, kol, vht, qid, kid, mask,
                                                  out_part, att_part);
  fc_kernel<<<dim3(4, 128), 256, 0, stream>>>(out_part, fcw, fcb, out0);
  reduce_att_kernel<<<dim3(4096), 256, 0, stream>>>(att_part, att_mean);
}